// Round 5
// baseline (334.273 us; speedup 1.0000x reference)
//
#include <hip/hip_runtime.h>

// MotifEnergy: fused motif dot -> segment logsumexp over nodes -> graph scatter.
// Shapes: M=1e6 motifs, N=1e5 nodes, R=4, d=16, NTAU=16, G=128.
//
// z = beta*ell is provably bounded -> single-pass sum(exp(z)), lse = log(sum).
//
// Round-10: rounds 3&4 pinned the motif pass at 60us across 6- and 12-deep
// MLP configs (occ 60% vs 35%) -> saturated scattered-request service wall:
// 2.1M random 64B L2-miss requests (12.8MB working set vs 4MB/XCD L2) at
// ~2.25 TB/s effective. Fix = make the gathers L2-HITS:
//  * r-sliced fp8 images [R][N][16B]; motif pass runs 4 phases (grid.y = r).
//    Per-phase working set 3.2MB < 4MB L2 -> steady-state gathers hit L2.
//  * cost: indices re-read per phase (+48MB sequential), slice fills ~102MB
//    full-line -> FETCH_SIZE predicted UP (~170MB) while dur drops.
//  * atomics unchanged (memory-side, bypass L2).
// If dur stays ~60us: atomic-rate wall confirmed -> atomic reduction next.
//
// ws layout: Q8[R][N][16B] (6.4MB) | K8 same | scal[4] | sums[N*R].

#define RR 4
#define DD 16
#define BETA_MAX 5.0f

typedef float v2f __attribute__((ext_vector_type(2)));
typedef float v4f __attribute__((ext_vector_type(4)));

#if defined(__has_builtin)
#if __has_builtin(__builtin_nontemporal_load)
#define NT_LOAD(p) __builtin_nontemporal_load(p)
#else
#define NT_LOAD(p) (*(p))
#endif
#else
#define NT_LOAD(p) (*(p))
#endif

__device__ __forceinline__ float softplus_f(float x) {
    return log1pf(__expf(x));
}

__device__ __forceinline__ int pack4_fp8(v4f f) {
    int w = 0;
    w = __builtin_amdgcn_cvt_pk_fp8_f32(f.x, f.y, w, false);  // bytes 0,1
    w = __builtin_amdgcn_cvt_pk_fp8_f32(f.z, f.w, w, true);   // bytes 2,3
    return w;
}

// fused: scalars + zero sums/out + convert Q3,K3 fp32->fp8 into r-SLICED
// layout: float4 j = (n, r, q) -> dst int index r*(N*4) + n*4 + q.
// Wave writes 4 slices x 64B contiguous = 4 lines per store: coalesced enough.
__global__ void me_init_convert(const float* __restrict__ raw_lam,
                                const float* __restrict__ raw_beta,
                                const float* __restrict__ Q3,
                                const float* __restrict__ K3,
                                int* __restrict__ Q8, int* __restrict__ K8,
                                float* __restrict__ scal, float* __restrict__ sums,
                                float* __restrict__ out,
                                int n4each, int N, int nr, int out_size) {
    int i = blockIdx.x * blockDim.x + threadIdx.x;
    if (i == 0) {
        float beta = fminf(softplus_f(raw_beta[0]), BETA_MAX);
        float lam  = softplus_f(raw_lam[0]);
        scal[0] = beta * 0.125f;   // beta / sqrt(R*d)
        scal[1] = lam / beta;
    }
    if (i < nr) sums[i] = 0.0f;
    if (i < out_size) out[i] = 0.0f;
    if (i < 2 * n4each) {
        const float* src = (i < n4each) ? Q3 : K3;
        int*         dst = (i < n4each) ? Q8 : K8;
        int j = (i < n4each) ? i : i - n4each;
        v4f f = NT_LOAD((const v4f*)src + j);
        int q = j & 3;
        int r = (j >> 2) & 3;
        int n = j >> 4;
        dst[(size_t)r * N * 4 + n * 4 + q] = pack4_fp8(f);
    }
}

// dot over d=16 for one r; T row comes from LDS (already scaled by beta/8).
__device__ __forceinline__ float dot16_fp8(int4 q8, int4 u8, int4 v8,
                                           const float* Trow) {
    float acc = 0.0f;
    const int qw[4] = {q8.x, q8.y, q8.z, q8.w};
    const int uw[4] = {u8.x, u8.y, u8.z, u8.w};
    const int vw[4] = {v8.x, v8.y, v8.z, v8.w};
#pragma unroll
    for (int j = 0; j < 4; ++j) {
        v2f ql = __builtin_amdgcn_cvt_pk_f32_fp8(qw[j], false);
        v2f qh = __builtin_amdgcn_cvt_pk_f32_fp8(qw[j], true);
        v2f ul = __builtin_amdgcn_cvt_pk_f32_fp8(uw[j], false);
        v2f uh = __builtin_amdgcn_cvt_pk_f32_fp8(uw[j], true);
        v2f vl = __builtin_amdgcn_cvt_pk_f32_fp8(vw[j], false);
        v2f vh = __builtin_amdgcn_cvt_pk_f32_fp8(vw[j], true);
        const v4f tw = *(const v4f*)(Trow + 4 * j);
        acc += ql.x * ul.x * vl.x * tw.x + ql.y * ul.y * vl.y * tw.y +
               qh.x * uh.x * vh.x * tw.z + qh.y * uh.y * vh.y * tw.w;
    }
    return acc;
}

// Phase kernel: blockIdx.y = r. One lane = one motif (2 motifs/lane for MLP).
// Gathers hit the r-slice (3.2MB working set -> L2-resident per XCD).
__global__ __launch_bounds__(256)
void me_motif_r(const int* __restrict__ c3, const int* __restrict__ u3,
                const int* __restrict__ v3, const int* __restrict__ tt,
                const int4* __restrict__ Q8, const int4* __restrict__ K8,
                const float* __restrict__ Tp, const float* __restrict__ scal,
                float* __restrict__ sums, int M, int N, int halfM) {
    __shared__ float Tl[256];   // NTAU(16) x DD(16), pre-scaled by beta/8
    Tl[threadIdx.x] = Tp[threadIdx.x] * scal[0];
    __syncthreads();

    int r = blockIdx.y;
    const int4* Qs = Q8 + (size_t)r * N;
    const int4* Ks = K8 + (size_t)r * N;

    int m0 = blockIdx.x * blockDim.x + threadIdx.x;
    if (m0 >= halfM) return;
    int m1 = m0 + halfM;
    bool h1 = (m1 < M);
    int m1c = h1 ? m1 : m0;

    int c0 = NT_LOAD(c3 + m0),  u0 = NT_LOAD(u3 + m0);
    int v0 = NT_LOAD(v3 + m0),  t0 = NT_LOAD(tt + m0);
    int c1 = NT_LOAD(c3 + m1c), u1 = NT_LOAD(u3 + m1c);
    int v1 = NT_LOAD(v3 + m1c), t1 = NT_LOAD(tt + m1c);

    int4 q0 = Qs[c0];
    int4 a0 = Ks[u0];
    int4 b0 = Ks[v0];
    int4 q1 = Qs[c1];
    int4 a1 = Ks[u1];
    int4 b1 = Ks[v1];

    float p0 = dot16_fp8(q0, a0, b0, &Tl[t0 * DD]);
    float p1 = dot16_fp8(q1, a1, b1, &Tl[t1 * DD]);

    atomicAdd(&sums[c0 * RR + r], __expf(p0));
    if (h1) atomicAdd(&sums[c1 * RR + r], __expf(p1));
}

// fp32 fallback (only if ws too small for the fp8 images)
__global__ void me_motif_f32(const int* __restrict__ c3, const int* __restrict__ u3,
                             const int* __restrict__ v3, const int* __restrict__ tt,
                             const float* __restrict__ Q3, const float* __restrict__ K3,
                             const float* __restrict__ Tp, const float* __restrict__ scal,
                             float* __restrict__ sums, int M) {
    int tid = blockIdx.x * blockDim.x + threadIdx.x;
    int m = tid >> 4;
    if (m >= M) return;
    int l = tid & 15;
    int r = l >> 2;
    int off = r * DD + ((l & 3) << 2);
    int dc  = (l & 3) << 2;

    int c = c3[m], u = u3[m], v = v3[m], t = tt[m];
    float bscale = scal[0];

    const float4 q  = *(const float4*)(Q3 + ((size_t)c * (RR * DD) + off));
    const float4 ku = *(const float4*)(K3 + ((size_t)u * (RR * DD) + off));
    const float4 kv = *(const float4*)(K3 + ((size_t)v * (RR * DD) + off));
    const float4 tw = *(const float4*)(Tp + ((size_t)t * DD + dc));

    float p = q.x * ku.x * kv.x * tw.x + q.y * ku.y * kv.y * tw.y +
              q.z * ku.z * kv.z * tw.z + q.w * ku.w * kv.w * tw.w;
    p += __shfl_xor(p, 1);
    p += __shfl_xor(p, 2);

    if ((l & 3) == 0) atomicAdd(&sums[c * RR + r], __expf(bscale * p));
}

__global__ void me_init_f32(const float* __restrict__ raw_lam,
                            const float* __restrict__ raw_beta,
                            float* __restrict__ scal, float* __restrict__ sums,
                            float* __restrict__ out, int nr, int out_size) {
    int i = blockIdx.x * blockDim.x + threadIdx.x;
    if (i == 0) {
        float beta = fminf(softplus_f(raw_beta[0]), BETA_MAX);
        float lam  = softplus_f(raw_lam[0]);
        scal[0] = beta * 0.125f;
        scal[1] = lam / beta;
    }
    if (i < nr) sums[i] = 0.0f;
    if (i < out_size) out[i] = 0.0f;
}

// per-(node,r) lse = log(sum); one float4 per node; LDS-accumulate per graph
// slot, flush * (lam/beta).
__global__ void me_node(const float* __restrict__ sums, const int* __restrict__ batch,
                        const float* __restrict__ scal, float* __restrict__ out,
                        int N, int out_size) {
    extern __shared__ float acc[];
    for (int i = threadIdx.x; i < out_size; i += blockDim.x) acc[i] = 0.0f;
    __syncthreads();

    for (int n = blockIdx.x * blockDim.x + threadIdx.x; n < N;
         n += gridDim.x * blockDim.x) {
        v4f s = *((const v4f*)sums + n);
        int g = batch[n] * RR;
        if (s.x > 0.0f) atomicAdd(&acc[g + 0], logf(s.x));
        if (s.y > 0.0f) atomicAdd(&acc[g + 1], logf(s.y));
        if (s.z > 0.0f) atomicAdd(&acc[g + 2], logf(s.z));
        if (s.w > 0.0f) atomicAdd(&acc[g + 3], logf(s.w));
    }
    __syncthreads();

    float coef = scal[1];
    for (int i = threadIdx.x; i < out_size; i += blockDim.x) {
        float a = acc[i];
        if (a != 0.0f) atomicAdd(&out[i], a * coef);
    }
}

extern "C" void kernel_launch(void* const* d_in, const int* in_sizes, int n_in,
                              void* d_out, int out_size, void* d_ws, size_t ws_size,
                              hipStream_t stream) {
    const int*   c3    = (const int*)d_in[0];
    const int*   u3    = (const int*)d_in[1];
    const int*   v3    = (const int*)d_in[2];
    const int*   tt    = (const int*)d_in[3];
    const int*   batch = (const int*)d_in[4];
    const float* Q3    = (const float*)d_in[5];
    const float* K3    = (const float*)d_in[6];
    const float* Tp    = (const float*)d_in[7];
    const float* rlam  = (const float*)d_in[8];
    const float* rbeta = (const float*)d_in[9];

    const int M   = in_sizes[0];
    const int nel = in_sizes[5];          // N*R*D floats per array
    const int N   = nel / (RR * DD);
    const int nr  = N * RR;

    const size_t fp8_bytes = (size_t)nel;                 // 1 B/elem per array
    const size_t need = 2 * fp8_bytes + (4 + (size_t)nr) * sizeof(float);

    float* out = (float*)d_out;

    if (ws_size >= need) {
        int*   Q8   = (int*)d_ws;
        int*   K8   = (int*)((char*)d_ws + fp8_bytes);
        float* scal = (float*)((char*)d_ws + 2 * fp8_bytes);
        float* sums = scal + 4;   // 16B-aligned (fp8_bytes % 16 == 0)

        const int n4each = nel / 4;
        {
            int tot = 2 * n4each;
            if (nr > tot) tot = nr;
            if (out_size > tot) tot = out_size;
            me_init_convert<<<(tot + 255) / 256, 256, 0, stream>>>(
                rlam, rbeta, Q3, K3, Q8, K8, scal, sums, out, n4each, N, nr, out_size);
        }
        {
            const int halfM = (M + 1) / 2;
            int gx = (halfM + 255) / 256;
            dim3 grid(gx, RR, 1);
            me_motif_r<<<grid, 256, 0, stream>>>(c3, u3, v3, tt, (const int4*)Q8,
                                                 (const int4*)K8, Tp, scal, sums,
                                                 M, N, halfM);
        }
        {
            int nblk = (N + 255) / 256;
            if (nblk > 256) nblk = 256;
            me_node<<<nblk, 256, (size_t)out_size * sizeof(float), stream>>>(
                sums, batch, scal, out, N, out_size);
        }
    } else {
        float* scal = (float*)d_ws;
        float* sums = scal + 4;
        {
            int tot = nr > out_size ? nr : out_size;
            me_init_f32<<<(tot + 255) / 256, 256, 0, stream>>>(rlam, rbeta, scal, sums, out, nr, out_size);
        }
        {
            long long threads = (long long)M * 16;
            int blocks = (int)((threads + 255) / 256);
            me_motif_f32<<<blocks, 256, 0, stream>>>(c3, u3, v3, tt, Q3, K3, Tp, scal, sums, M);
        }
        {
            int nblk = (N + 255) / 256;
            if (nblk > 256) nblk = 256;
            me_node<<<nblk, 256, (size_t)out_size * sizeof(float), stream>>>(
                sums, batch, scal, out, N, out_size);
        }
    }
}

// Round 6
// 180.141 us; speedup vs baseline: 1.8556x; 1.8556x over previous
//
#include <hip/hip_runtime.h>

// MotifEnergy: fused motif dot -> segment logsumexp over nodes -> graph scatter.
// Shapes: M=1e6 motifs, N=1e5 nodes, R=4, d=16, NTAU=16, G=128.
//
// z = beta*ell is provably bounded -> single-pass sum(exp(z)), lse = log(sum).
//
// Round-11: REVERT to the round-3 best (181.0 us total, motif 60.0 us).
// Evidence ledger:
//  * R3 (2 motifs/lane, 6 gathers in flight, occ 60%): motif 60.0 us.
//  * R4 (4 motifs/lane, 12 in flight, occ 35%): 60.9 us -> MLP-insensitive.
//  * R5 (r-phased, 16B divergent gathers, 4x atomics): 214 us, FETCH DOWN,
//    WRITE 4x -> time tracks scattered line-request count (~75 G req/s),
//    not bytes, not L2 hit rate.
// Request floor for this op: 3 random 64B gathers + 1 wave-merged atomic
// + ~0.4 index lines per motif = ~4.4M requests = ~58 us. R3 sits on it.
// Sorting by c to cut Q-gather/atomic requests costs an equivalent number
// of scattered sort requests (measured wash) -> structural floor.
//
// ws layout: Q8[6.4MB] | K8[6.4MB] | scal[4] | sums[N*R].

#define RR 4
#define DD 16
#define BETA_MAX 5.0f

typedef float v2f __attribute__((ext_vector_type(2)));
typedef float v4f __attribute__((ext_vector_type(4)));

#if defined(__has_builtin)
#if __has_builtin(__builtin_nontemporal_load)
#define NT_LOAD(p) __builtin_nontemporal_load(p)
#else
#define NT_LOAD(p) (*(p))
#endif
#else
#define NT_LOAD(p) (*(p))
#endif

__device__ __forceinline__ float softplus_f(float x) {
    return log1pf(__expf(x));
}

__device__ __forceinline__ int pack4_fp8(v4f f) {
    int w = 0;
    w = __builtin_amdgcn_cvt_pk_fp8_f32(f.x, f.y, w, false);  // bytes 0,1
    w = __builtin_amdgcn_cvt_pk_fp8_f32(f.z, f.w, w, true);   // bytes 2,3
    return w;
}

// fused: scalars + zero sums/out + convert Q3,K3 fp32->fp8, 4 elems/thread.
// lane reads one float4 (consecutive lanes -> consecutive 16B: coalesced),
// writes one packed int (consecutive 4B: coalesced). Interleaved [N][R][16B]
// layout preserved (node row = 64B shared by 4 lanes in the motif pass).
__global__ void me_init_convert(const float* __restrict__ raw_lam,
                                const float* __restrict__ raw_beta,
                                const float* __restrict__ Q3,
                                const float* __restrict__ K3,
                                int* __restrict__ Q8, int* __restrict__ K8,
                                float* __restrict__ scal, float* __restrict__ sums,
                                float* __restrict__ out,
                                int n4each, int nr, int out_size) {
    int i = blockIdx.x * blockDim.x + threadIdx.x;
    if (i == 0) {
        float beta = fminf(softplus_f(raw_beta[0]), BETA_MAX);
        float lam  = softplus_f(raw_lam[0]);
        scal[0] = beta * 0.125f;   // beta / sqrt(R*d)
        scal[1] = lam / beta;
    }
    if (i < nr) sums[i] = 0.0f;
    if (i < out_size) out[i] = 0.0f;
    if (i < 2 * n4each) {
        const float* src = (i < n4each) ? Q3 : K3;
        int*         dst = (i < n4each) ? Q8 : K8;
        int j = (i < n4each) ? i : i - n4each;
        v4f f = NT_LOAD((const v4f*)src + j);
        dst[j] = pack4_fp8(f);
    }
}

// 4 lanes per motif: lane k handles r=k; one int4 load = full 16-elem d-row.
__device__ __forceinline__ float dot16_fp8(int4 q8, int4 u8, int4 v8,
                                           const float* __restrict__ Trow) {
    float acc = 0.0f;
    const int qw[4] = {q8.x, q8.y, q8.z, q8.w};
    const int uw[4] = {u8.x, u8.y, u8.z, u8.w};
    const int vw[4] = {v8.x, v8.y, v8.z, v8.w};
#pragma unroll
    for (int j = 0; j < 4; ++j) {
        v2f ql = __builtin_amdgcn_cvt_pk_f32_fp8(qw[j], false);
        v2f qh = __builtin_amdgcn_cvt_pk_f32_fp8(qw[j], true);
        v2f ul = __builtin_amdgcn_cvt_pk_f32_fp8(uw[j], false);
        v2f uh = __builtin_amdgcn_cvt_pk_f32_fp8(uw[j], true);
        v2f vl = __builtin_amdgcn_cvt_pk_f32_fp8(vw[j], false);
        v2f vh = __builtin_amdgcn_cvt_pk_f32_fp8(vw[j], true);
        const v4f tw = *(const v4f*)(Trow + 4 * j);
        acc += ql.x * ul.x * vl.x * tw.x + ql.y * ul.y * vl.y * tw.y +
               qh.x * uh.x * vh.x * tw.z + qh.y * uh.y * vh.y * tw.w;
    }
    return acc;
}

// 2 motifs per lane (m0 and m0+half): 6 scattered gathers in flight per lane.
// Tp reads stay in global (1KB, L1-hot; R4 showed LDS-staging is neutral and
// costs VGPR/occupancy).
__global__ __launch_bounds__(256)
void me_motif_8(const int* __restrict__ c3, const int* __restrict__ u3,
                const int* __restrict__ v3, const int* __restrict__ tt,
                const int4* __restrict__ Q8, const int4* __restrict__ K8,
                const float* __restrict__ Tp, const float* __restrict__ scal,
                float* __restrict__ sums, int M, int half) {
    int tid = blockIdx.x * blockDim.x + threadIdx.x;
    int m0 = tid >> 2;
    if (m0 >= half) return;
    int k = tid & 3;   // r index
    int m1 = m0 + half;
    bool has1 = (m1 < M);
    int m1c = has1 ? m1 : m0;

    int c0 = NT_LOAD(c3 + m0);
    int u0 = NT_LOAD(u3 + m0);
    int v0 = NT_LOAD(v3 + m0);
    int t0 = NT_LOAD(tt + m0);
    int c1 = NT_LOAD(c3 + m1c);
    int u1 = NT_LOAD(u3 + m1c);
    int v1 = NT_LOAD(v3 + m1c);
    int t1 = NT_LOAD(tt + m1c);

    float bscale = scal[0];

    int4 q0 = Q8[(size_t)c0 * 4 + k];
    int4 a0 = K8[(size_t)u0 * 4 + k];
    int4 b0 = K8[(size_t)v0 * 4 + k];
    int4 q1 = Q8[(size_t)c1 * 4 + k];
    int4 a1 = K8[(size_t)u1 * 4 + k];
    int4 b1 = K8[(size_t)v1 * 4 + k];

    float p0 = dot16_fp8(q0, a0, b0, Tp + (size_t)t0 * DD);
    float p1 = dot16_fp8(q1, a1, b1, Tp + (size_t)t1 * DD);

    atomicAdd(&sums[c0 * RR + k], __expf(bscale * p0));
    if (has1) atomicAdd(&sums[c1 * RR + k], __expf(bscale * p1));
}

// fp32 fallback (only if ws too small for the fp8 images)
__global__ void me_motif_f32(const int* __restrict__ c3, const int* __restrict__ u3,
                             const int* __restrict__ v3, const int* __restrict__ tt,
                             const float* __restrict__ Q3, const float* __restrict__ K3,
                             const float* __restrict__ Tp, const float* __restrict__ scal,
                             float* __restrict__ sums, int M) {
    int tid = blockIdx.x * blockDim.x + threadIdx.x;
    int m = tid >> 4;
    if (m >= M) return;
    int l = tid & 15;
    int r = l >> 2;
    int off = r * DD + ((l & 3) << 2);
    int dc  = (l & 3) << 2;

    int c = c3[m], u = u3[m], v = v3[m], t = tt[m];
    float bscale = scal[0];

    const float4 q  = *(const float4*)(Q3 + ((size_t)c * (RR * DD) + off));
    const float4 ku = *(const float4*)(K3 + ((size_t)u * (RR * DD) + off));
    const float4 kv = *(const float4*)(K3 + ((size_t)v * (RR * DD) + off));
    const float4 tw = *(const float4*)(Tp + ((size_t)t * DD + dc));

    float p = q.x * ku.x * kv.x * tw.x + q.y * ku.y * kv.y * tw.y +
              q.z * ku.z * kv.z * tw.z + q.w * ku.w * kv.w * tw.w;
    p += __shfl_xor(p, 1);
    p += __shfl_xor(p, 2);

    if ((l & 3) == 0) atomicAdd(&sums[c * RR + r], __expf(bscale * p));
}

__global__ void me_init_f32(const float* __restrict__ raw_lam,
                            const float* __restrict__ raw_beta,
                            float* __restrict__ scal, float* __restrict__ sums,
                            float* __restrict__ out, int nr, int out_size) {
    int i = blockIdx.x * blockDim.x + threadIdx.x;
    if (i == 0) {
        float beta = fminf(softplus_f(raw_beta[0]), BETA_MAX);
        float lam  = softplus_f(raw_lam[0]);
        scal[0] = beta * 0.125f;
        scal[1] = lam / beta;
    }
    if (i < nr) sums[i] = 0.0f;
    if (i < out_size) out[i] = 0.0f;
}

// per-(node,r) lse = log(sum); one float4 per node; LDS-accumulate per graph
// slot, flush * (lam/beta).
__global__ void me_node(const float* __restrict__ sums, const int* __restrict__ batch,
                        const float* __restrict__ scal, float* __restrict__ out,
                        int N, int out_size) {
    extern __shared__ float acc[];
    for (int i = threadIdx.x; i < out_size; i += blockDim.x) acc[i] = 0.0f;
    __syncthreads();

    for (int n = blockIdx.x * blockDim.x + threadIdx.x; n < N;
         n += gridDim.x * blockDim.x) {
        v4f s = *((const v4f*)sums + n);
        int g = batch[n] * RR;
        if (s.x > 0.0f) atomicAdd(&acc[g + 0], logf(s.x));
        if (s.y > 0.0f) atomicAdd(&acc[g + 1], logf(s.y));
        if (s.z > 0.0f) atomicAdd(&acc[g + 2], logf(s.z));
        if (s.w > 0.0f) atomicAdd(&acc[g + 3], logf(s.w));
    }
    __syncthreads();

    float coef = scal[1];
    for (int i = threadIdx.x; i < out_size; i += blockDim.x) {
        float a = acc[i];
        if (a != 0.0f) atomicAdd(&out[i], a * coef);
    }
}

extern "C" void kernel_launch(void* const* d_in, const int* in_sizes, int n_in,
                              void* d_out, int out_size, void* d_ws, size_t ws_size,
                              hipStream_t stream) {
    const int*   c3    = (const int*)d_in[0];
    const int*   u3    = (const int*)d_in[1];
    const int*   v3    = (const int*)d_in[2];
    const int*   tt    = (const int*)d_in[3];
    const int*   batch = (const int*)d_in[4];
    const float* Q3    = (const float*)d_in[5];
    const float* K3    = (const float*)d_in[6];
    const float* Tp    = (const float*)d_in[7];
    const float* rlam  = (const float*)d_in[8];
    const float* rbeta = (const float*)d_in[9];

    const int M   = in_sizes[0];
    const int nel = in_sizes[5];          // N*R*D floats per array
    const int N   = nel / (RR * DD);
    const int nr  = N * RR;

    const size_t fp8_bytes = (size_t)nel;                 // 1 B/elem per array
    const size_t need = 2 * fp8_bytes + (4 + (size_t)nr) * sizeof(float);

    float* out = (float*)d_out;

    if (ws_size >= need) {
        int*   Q8   = (int*)d_ws;
        int*   K8   = (int*)((char*)d_ws + fp8_bytes);
        float* scal = (float*)((char*)d_ws + 2 * fp8_bytes);
        float* sums = scal + 4;   // 16B-aligned (fp8_bytes % 16 == 0)

        const int n4each = nel / 4;
        {
            int tot = 2 * n4each;
            if (nr > tot) tot = nr;
            if (out_size > tot) tot = out_size;
            me_init_convert<<<(tot + 255) / 256, 256, 0, stream>>>(
                rlam, rbeta, Q3, K3, Q8, K8, scal, sums, out, n4each, nr, out_size);
        }
        {
            const int half = (M + 1) / 2;
            long long threads = (long long)half * 4;
            int blocks = (int)((threads + 255) / 256);
            me_motif_8<<<blocks, 256, 0, stream>>>(c3, u3, v3, tt, (const int4*)Q8,
                                                   (const int4*)K8, Tp, scal, sums,
                                                   M, half);
        }
        {
            int nblk = (N + 255) / 256;
            if (nblk > 256) nblk = 256;
            me_node<<<nblk, 256, (size_t)out_size * sizeof(float), stream>>>(
                sums, batch, scal, out, N, out_size);
        }
    } else {
        float* scal = (float*)d_ws;
        float* sums = scal + 4;
        {
            int tot = nr > out_size ? nr : out_size;
            me_init_f32<<<(tot + 255) / 256, 256, 0, stream>>>(rlam, rbeta, scal, sums, out, nr, out_size);
        }
        {
            long long threads = (long long)M * 16;
            int blocks = (int)((threads + 255) / 256);
            me_motif_f32<<<blocks, 256, 0, stream>>>(c3, u3, v3, tt, Q3, K3, Tp, scal, sums, M);
        }
        {
            int nblk = (N + 255) / 256;
            if (nblk > 256) nblk = 256;
            me_node<<<nblk, 256, (size_t)out_size * sizeof(float), stream>>>(
                sums, batch, scal, out, N, out_size);
        }
    }
}